// Round 4
// baseline (262.198 us; speedup 1.0000x reference)
//
#include <hip/hip_runtime.h>
#include <hip/hip_bf16.h>

// ---------------------------------------------------------------------------
// TransformerEncoder forward on MI355X (gfx950). Round 3:
//   - weight transpose pre-pass DELETED: GEMM B-staging reads original fp32
//     W[K][N], does 4x4 register micro-transpose + fp32->bf16, ds_write_b64
//     into XOR-swizzled LDS. A-side keeps global_load_lds.
//   - XCD-aware block swizzle, m-fastest: blocks sharing a B-panel colocate
//     on one XCD (L2-resident panel).
//   - Q/K flat + small permute_qk gather; attention reads [h][row][d].
// ---------------------------------------------------------------------------

typedef __bf16 bf16_t;
typedef __bf16 bf16x8 __attribute__((ext_vector_type(8)));
typedef float  f32x4  __attribute__((ext_vector_type(4)));

#define SEQL 512
#define DM   2048
#define FFH  8192
#define NH   16
#define DHD  128
#define PST  ((size_t)SEQL*DM)   // partial-slice stride

__device__ __forceinline__ unsigned short bfbits(float f){
  bf16_t h = (bf16_t)f;
  return __builtin_bit_cast(unsigned short, h);
}
__device__ __forceinline__ unsigned int pack2(float a, float b){
  return (unsigned int)bfbits(a) | ((unsigned int)bfbits(b) << 16);
}

__device__ __forceinline__ void gll16(const bf16_t* g, bf16_t* l){
  __builtin_amdgcn_global_load_lds(
      (const __attribute__((address_space(1))) void*)g,
      (__attribute__((address_space(3))) void*)l, 16, 0, 0);
}

// ---------------------------------------------------------------------------
// fp32 -> bf16 elementwise convert (for `sequence`)
__global__ __launch_bounds__(256)
void cvt_bf16(const float* __restrict__ in, bf16_t* __restrict__ out){
  const int i = (blockIdx.x * 256 + threadIdx.x) * 4;
  const float4 v = *(const float4*)(in + i);
  ushort4 o;
  o.x = bfbits(v.x); o.y = bfbits(v.y); o.z = bfbits(v.z); o.w = bfbits(v.w);
  *(ushort4*)(out + i) = o;
}

// ---------------------------------------------------------------------------
// GEMM: C[512][N] = A[512][K](bf16) @ W[K][N](fp32, transposed on the fly).
// 64x128 tile, BK=32, 256 threads, 4 waves (wave w -> 32x64 sub-tile).
// Grid: 1-D, XCD-swizzled, m-fastest: s = (bid&7)*(nwg/8) + bid>>3;
//       mt = s&7, nt = (s>>3)%nn, zt = (s>>3)/nn.
// PERM=1 (AO): B-row for GEMM-k kr sources W row 16*(kr&127)+(kr>>7).
constexpr int E_PART = 0;  // fp32 partial (no bias) -> outF + zt*PST
constexpr int E_QKV  = 1;  // [0,2k)->Qf flat, [2k,4k)->Kf flat, rest->Vt[h][d][key]
constexpr int E_FFN1 = 2;  // bias + gelu -> bf16 [512][FFH]

template<int EPI, int PERM>
__global__ __launch_bounds__(256, 4)
void gemmF(const bf16_t* __restrict__ A,
           const float* __restrict__ W0p, const float* __restrict__ W1p,
           const float* __restrict__ W2p,
           const float* __restrict__ b0p, const float* __restrict__ b1p,
           const float* __restrict__ b2p,
           float* __restrict__ outF, bf16_t* __restrict__ o0,
           bf16_t* __restrict__ o1, bf16_t* __restrict__ o2,
           int nn, int Nw, int K, int Kc)
{
  __shared__ bf16_t sA[2][64*32];
  __shared__ bf16_t sB[2][128*32];
  const int tid  = threadIdx.x;
  const int lane = tid & 63, w = tid >> 6;
  const int wr4 = w >> 1, wc = w & 1;
  const int c = lane & 15, g = lane >> 4;

  // grid decode (XCD swizzle, m-fastest)
  const int nwg = gridDim.x, cpx = nwg >> 3;
  const int sblk = (blockIdx.x & 7) * cpx + (blockIdx.x >> 3);
  const int mt = sblk & 7, q = sblk >> 3;
  const int nt = q % nn, zt = q / nn;
  const int m0 = mt * 64, k0 = zt * Kc;

  // weight select (QKV: three separate [2048][2048] sources)
  const float* Wp = W0p; int nb0 = nt * 128;
  if constexpr (EPI == E_QKV){
    if (nt >= 32){ Wp = W2p; nb0 = (nt - 32) * 128; }
    else if (nt >= 16){ Wp = W1p; nb0 = (nt - 16) * 128; }
  }

  // A staging (global_load_lds, pre-swizzled 16B slot within each 64B k-row)
  const int sr = tid >> 2, ss = tid & 3;
  const int scol = ((ss ^ ((sr >> 1) & 3)) << 3);
  const bf16_t* Asrc = A + (size_t)(m0 + sr) * K + k0 + scol;

  // B staging (reg micro-transpose): thread covers rows kb..kb+3, cols 4*bn4..+3
  const int bn4 = tid & 31;
  const int kb  = (tid >> 5) * 4;
  const float* Bsrc = Wp + nb0 + bn4 * 4;

  // fragment read offsets
  int raA[2], raB[4];
#pragma unroll
  for (int m = 0; m < 2; ++m){
    const int r = wr4*32 + m*16 + c;
    raA[m] = r*32 + ((g ^ ((r >> 1) & 3)) << 3);
  }
#pragma unroll
  for (int n = 0; n < 4; ++n){
    const int r = wc*64 + n*16 + c;
    raB[n] = r*32 + ((g ^ ((r >> 2) & 3)) << 3);
  }

  f32x4 wr[4];

#define LOADW(kt) {                                                         \
    const int kk = k0 + (kt)*32 + kb;                                       \
    _Pragma("unroll")                                                       \
    for (int i = 0; i < 4; ++i){                                            \
      const int kr = kk + i;                                                \
      const int krow = PERM ? (((kr & 127) << 4) + (kr >> 7)) : kr;         \
      wr[i] = *(const f32x4*)(Bsrc + (size_t)krow * Nw);                    \
    } }

#define STAGEA(bf, kt) gll16(Asrc + (size_t)(kt)*32, &sA[bf][tid*8]);

#define WRITEB(bf) {                                                        \
    _Pragma("unroll")                                                       \
    for (int j = 0; j < 4; ++j){                                            \
      const int n = bn4*4 + j;                                              \
      const int el = n*32 + (kb ^ (((n >> 2) & 3) << 3));                   \
      uint2 v2;                                                             \
      v2.x = pack2(wr[0][j], wr[1][j]);                                     \
      v2.y = pack2(wr[2][j], wr[3][j]);                                     \
      *(uint2*)&sB[bf][el] = v2;                                            \
    } }

  f32x4 acc[2][4] = {};
  const int nk = Kc >> 5;

  LOADW(0);
  STAGEA(0, 0);
  WRITEB(0);
  __syncthreads();

  int buf = 0;
  for (int kt = 0; kt < nk; ++kt){
    const int nb = buf ^ 1;
    if (kt + 1 < nk){ LOADW(kt + 1); STAGEA(nb, kt + 1); }
    bf16x8 af[2], bq4[4];
#pragma unroll
    for (int m = 0; m < 2; ++m) af[m] = *(const bf16x8*)&sA[buf][raA[m]];
#pragma unroll
    for (int n = 0; n < 4; ++n) bq4[n] = *(const bf16x8*)&sB[buf][raB[n]];
#pragma unroll
    for (int m = 0; m < 2; ++m)
#pragma unroll
      for (int n = 0; n < 4; ++n)
        acc[m][n] = __builtin_amdgcn_mfma_f32_16x16x32_bf16(af[m], bq4[n], acc[m][n], 0,0,0);
    if (kt + 1 < nk){ WRITEB(nb); }
    __syncthreads();
    buf = nb;
  }
#undef LOADW
#undef STAGEA
#undef WRITEB

  // epilogue: row = m0 + wr4*32 + m*16 + 4g + rr, col = nt*128 + wc*64 + n*16 + c
#pragma unroll
  for (int n = 0; n < 4; ++n){
    const int col = nt*128 + wc*64 + n*16 + c;
#pragma unroll
    for (int m = 0; m < 2; ++m){
      const int row0 = m0 + wr4*32 + m*16 + 4*g;
      const f32x4 a4 = acc[m][n];
      if constexpr (EPI == E_PART){
        float* dst = outF + (size_t)zt * PST;
#pragma unroll
        for (int rr = 0; rr < 4; ++rr)
          dst[(size_t)(row0+rr)*DM + col] = a4[rr];
      } else if constexpr (EPI == E_QKV){
        if (col < DM){
          const float bv = b0p[col];
#pragma unroll
          for (int rr = 0; rr < 4; ++rr)
            o0[(size_t)(row0+rr)*DM + col] = (bf16_t)(a4[rr] + bv);
        } else if (col < 2*DM){
          const int cc = col - DM;
          const float bv = b1p[cc];
#pragma unroll
          for (int rr = 0; rr < 4; ++rr)
            o1[(size_t)(row0+rr)*DM + cc] = (bf16_t)(a4[rr] + bv);
        } else {
          const int cc = col - 2*DM;
          const float bv = b2p[cc];
          const int hh = cc & 15, dd = cc >> 4;
          unsigned short us[4];
#pragma unroll
          for (int rr = 0; rr < 4; ++rr) us[rr] = bfbits(a4[rr] + bv);
          *(ushort4*)&o2[(size_t)(hh*DHD + dd)*SEQL + row0] =
              make_ushort4(us[0], us[1], us[2], us[3]);
        }
      } else if constexpr (EPI == E_FFN1){
        const float bv = b0p[col];
#pragma unroll
        for (int rr = 0; rr < 4; ++rr){
          const float v = a4[rr] + bv;
          const float z = v * (v*v*0.044715f + 1.0f) * 1.5957691216f;
          const float gg = v / (1.0f + __expf(-z));
          o0[(size_t)(row0+rr)*FFH + col] = (bf16_t)gg;
        }
      }
    }
  }
}

// ---------------------------------------------------------------------------
// Gather Q/K flat [row][16d+h] -> head layout [h][row][d] (pure bit-move).
__global__ __launch_bounds__(256)
void permute_qk(const bf16_t* __restrict__ Qf, const bf16_t* __restrict__ Kf,
                bf16_t* __restrict__ Qhd, bf16_t* __restrict__ Khd)
{
  const int row = blockIdx.x, which = blockIdx.y, tid = threadIdx.x;
  const bf16_t* src = (which ? Kf : Qf) + (size_t)row * DM;
  bf16_t* dst = which ? Khd : Qhd;
  const int hh = tid >> 4, d0 = (tid & 15) * 8;
  unsigned short us[8];
#pragma unroll
  for (int j = 0; j < 8; ++j)
    us[j] = __builtin_bit_cast(unsigned short, src[(d0 + j)*NH + hh]);
  uint4 o;
  o.x = (unsigned)us[0] | ((unsigned)us[1] << 16);
  o.y = (unsigned)us[2] | ((unsigned)us[3] << 16);
  o.z = (unsigned)us[4] | ((unsigned)us[5] << 16);
  o.w = (unsigned)us[6] | ((unsigned)us[7] << 16);
  *(uint4*)&dst[(size_t)hh*(SEQL*DHD) + (size_t)row*DHD + d0] = o;
}

// ---------------------------------------------------------------------------
// Attention: one block per (32 q-rows, head). Full softmax over 512 keys.
// Qh/Kh: [h][row][d]  Vt: [h][d][key]  Aout: [row][h*128+d] bf16
__global__ __launch_bounds__(256)
void attn_kernel(const bf16_t* __restrict__ Qh, const bf16_t* __restrict__ Kh,
                 const bf16_t* __restrict__ Vt, bf16_t* __restrict__ Aout)
{
  __shared__ bf16_t Pl[32*512];
  __shared__ float redm[4][32];
  __shared__ float reds[4][32];
  const int tid = threadIdx.x;
  const int lane = tid & 63, w = tid >> 6;
  const int c = lane & 15, g = lane >> 4;
  const int h = blockIdx.y;
  const int rb = blockIdx.x * 32;
  const bf16_t* Qb = Qh + (size_t)h * (SEQL*DHD);
  const bf16_t* Kb = Kh + (size_t)h * (SEQL*DHD);
  const bf16_t* Vb = Vt + (size_t)h * (SEQL*DHD);

  bf16x8 qf[2][4];
#pragma unroll
  for (int a = 0; a < 2; ++a)
#pragma unroll
    for (int ks = 0; ks < 4; ++ks)
      qf[a][ks] = *(const bf16x8*)(Qb + (size_t)(rb + a*16 + c)*DHD + ks*32 + g*8);

  f32x4 s[2][8] = {};
#pragma unroll
  for (int ks = 0; ks < 4; ++ks)
#pragma unroll
    for (int b = 0; b < 8; ++b){
      const bf16x8 kf = *(const bf16x8*)(Kb + (size_t)(w*128 + b*16 + c)*DHD + ks*32 + g*8);
      s[0][b] = __builtin_amdgcn_mfma_f32_16x16x32_bf16(qf[0][ks], kf, s[0][b], 0,0,0);
      s[1][b] = __builtin_amdgcn_mfma_f32_16x16x32_bf16(qf[1][ks], kf, s[1][b], 0,0,0);
    }
  // 1/sqrt(2048) score scale
#pragma unroll
  for (int a = 0; a < 2; ++a)
#pragma unroll
    for (int b = 0; b < 8; ++b)
#pragma unroll
      for (int rr = 0; rr < 4; ++rr) s[a][b][rr] *= 0.022097086912079612f;

  float mx[2][4], sm[2][4], inv[2][4];
#pragma unroll
  for (int a = 0; a < 2; ++a)
#pragma unroll
    for (int rr = 0; rr < 4; ++rr){
      float m = s[a][0][rr];
#pragma unroll
      for (int b = 1; b < 8; ++b) m = fmaxf(m, s[a][b][rr]);
#pragma unroll
      for (int off = 1; off < 16; off <<= 1) m = fmaxf(m, __shfl_xor(m, off));
      mx[a][rr] = m;
    }
  if (c == 0)
#pragma unroll
    for (int a = 0; a < 2; ++a)
#pragma unroll
      for (int rr = 0; rr < 4; ++rr) redm[w][a*16 + 4*g + rr] = mx[a][rr];
  __syncthreads();
#pragma unroll
  for (int a = 0; a < 2; ++a)
#pragma unroll
    for (int rr = 0; rr < 4; ++rr){
      const int lr = a*16 + 4*g + rr;
      mx[a][rr] = fmaxf(fmaxf(redm[0][lr], redm[1][lr]), fmaxf(redm[2][lr], redm[3][lr]));
      sm[a][rr] = 0.f;
    }
#pragma unroll
  for (int a = 0; a < 2; ++a)
#pragma unroll
    for (int b = 0; b < 8; ++b)
#pragma unroll
      for (int rr = 0; rr < 4; ++rr){
        const float p = __expf(s[a][b][rr] - mx[a][rr]);
        s[a][b][rr] = p;
        sm[a][rr] += p;
      }
#pragma unroll
  for (int a = 0; a < 2; ++a)
#pragma unroll
    for (int rr = 0; rr < 4; ++rr){
#pragma unroll
      for (int off = 1; off < 16; off <<= 1) sm[a][rr] += __shfl_xor(sm[a][rr], off);
    }
  if (c == 0)
#pragma unroll
    for (int a = 0; a < 2; ++a)
#pragma unroll
      for (int rr = 0; rr < 4; ++rr) reds[w][a*16 + 4*g + rr] = sm[a][rr];
  __syncthreads();
#pragma unroll
  for (int a = 0; a < 2; ++a)
#pragma unroll
    for (int rr = 0; rr < 4; ++rr){
      const int lr = a*16 + 4*g + rr;
      inv[a][rr] = 1.0f / (reds[0][lr] + reds[1][lr] + reds[2][lr] + reds[3][lr]);
    }

#pragma unroll
  for (int a = 0; a < 2; ++a)
#pragma unroll
    for (int b = 0; b < 8; ++b)
#pragma unroll
      for (int rr = 0; rr < 4; ++rr){
        const int lr  = a*16 + 4*g + rr;
        const int key = w*128 + b*16 + c;
        const int slot = (key >> 3) ^ (lr & 7);
        Pl[lr*512 + slot*8 + (key & 7)] = (bf16_t)(s[a][b][rr] * inv[a][rr]);
      }
  __syncthreads();

  f32x4 o[2][2] = {};
  const int dw = w * 32;
#pragma unroll
  for (int kst = 0; kst < 16; ++kst){
    bf16x8 pa2[2];
#pragma unroll
    for (int a = 0; a < 2; ++a){
      const int r = a*16 + c;
      const int slot = (kst*4 + g) ^ (r & 7);
      pa2[a] = *(const bf16x8*)&Pl[r*512 + slot*8];
    }
#pragma unroll
    for (int db = 0; db < 2; ++db){
      const bf16x8 vf = *(const bf16x8*)(Vb + (size_t)(dw + db*16 + c)*SEQL + kst*32 + g*8);
      o[0][db] = __builtin_amdgcn_mfma_f32_16x16x32_bf16(pa2[0], vf, o[0][db], 0,0,0);
      o[1][db] = __builtin_amdgcn_mfma_f32_16x16x32_bf16(pa2[1], vf, o[1][db], 0,0,0);
    }
  }
#pragma unroll
  for (int a = 0; a < 2; ++a)
#pragma unroll
    for (int db = 0; db < 2; ++db)
#pragma unroll
      for (int rr = 0; rr < 4; ++rr){
        const int row  = rb + a*16 + 4*g + rr;
        const int col2 = h*DHD + dw + db*16 + c;
        Aout[(size_t)row*DM + col2] = (bf16_t)o[a][db][rr];
      }
}

// ---------------------------------------------------------------------------
// reduce 4 split-K partials + bias + positional encoding -> X fp32 + XB bf16
__global__ __launch_bounds__(256)
void reduce_pos(const float* __restrict__ P, const float* __restrict__ bias,
                float* __restrict__ X, bf16_t* __restrict__ XB)
{
  const int row = blockIdx.x, c0 = threadIdx.x * 8;
  const size_t base = (size_t)row * DM + c0;
  float y[8];
#pragma unroll
  for (int j = 0; j < 8; ++j) y[j] = bias[c0 + j];
#pragma unroll
  for (int s = 0; s < 4; ++s){
    const float4 v0 = *(const float4*)(P + s*PST + base);
    const float4 v1 = *(const float4*)(P + s*PST + base + 4);
    y[0]+=v0.x; y[1]+=v0.y; y[2]+=v0.z; y[3]+=v0.w;
    y[4]+=v1.x; y[5]+=v1.y; y[6]+=v1.z; y[7]+=v1.w;
  }
#pragma unroll
  for (int j = 0; j < 8; ++j){
    const int col = c0 + j;
    const float fr  = 1e-4f * __expf(-(float)(col >> 1) * (1.0f/1024.0f));
    const float ang = (float)row * fr;
    y[j] += (col & 1) ? __cosf(ang) : __sinf(ang);
  }
  *(float4*)(X + base)     = make_float4(y[0], y[1], y[2], y[3]);
  *(float4*)(X + base + 4) = make_float4(y[4], y[5], y[6], y[7]);
  uint4 ob;
  ob.x = pack2(y[0], y[1]); ob.y = pack2(y[2], y[3]);
  ob.z = pack2(y[4], y[5]); ob.w = pack2(y[6], y[7]);
  *(uint4*)&XB[base] = ob;
}

// ---------------------------------------------------------------------------
// reduce 4 split-K partials + bias + residual, then row-LayerNorm(2048).
template<int WB>
__global__ __launch_bounds__(256)
void reduce_ln(const float* __restrict__ P, const float* __restrict__ bias,
               const float* __restrict__ resid, const float* __restrict__ gam,
               const float* __restrict__ bet, float* __restrict__ outF,
               bf16_t* __restrict__ outB)
{
  const int row = blockIdx.x, tid = threadIdx.x, c0 = tid * 8;
  const size_t base = (size_t)row * DM + c0;
  float y[8];
  {
    const float4 r0 = *(const float4*)(resid + base);
    const float4 r1 = *(const float4*)(resid + base + 4);
    y[0]=r0.x; y[1]=r0.y; y[2]=r0.z; y[3]=r0.w;
    y[4]=r1.x; y[5]=r1.y; y[6]=r1.z; y[7]=r1.w;
  }
#pragma unroll
  for (int j = 0; j < 8; ++j) y[j] += bias[c0 + j];
#pragma unroll
  for (int s = 0; s < 4; ++s){
    const float4 v0 = *(const float4*)(P + s*PST + base);
    const float4 v1 = *(const float4*)(P + s*PST + base + 4);
    y[0]+=v0.x; y[1]+=v0.y; y[2]+=v0.z; y[3]+=v0.w;
    y[4]+=v1.x; y[5]+=v1.y; y[6]+=v1.z; y[7]+=v1.w;
  }
  float sm = 0.f, qs = 0.f;
#pragma unroll
  for (int j = 0; j < 8; ++j){ sm += y[j]; qs += y[j]*y[j]; }
#pragma unroll
  for (int off = 32; off >= 1; off >>= 1){
    sm += __shfl_xor(sm, off); qs += __shfl_xor(qs, off);
  }
  __shared__ float rs[4], rq[4];
  const int w = tid >> 6;
  if ((tid & 63) == 0){ rs[w] = sm; rq[w] = qs; }
  __syncthreads();
  sm = rs[0]+rs[1]+rs[2]+rs[3];
  qs = rq[0]+rq[1]+rq[2]+rq[3];
  const float mu   = sm * (1.0f/2048.0f);
  const float var  = qs * (1.0f/2048.0f) - mu*mu;
  const float rstd = rsqrtf(var + 1e-5f);
  const float4 g0 = *(const float4*)(gam + c0);
  const float4 g1 = *(const float4*)(gam + c0 + 4);
  const float4 b0 = *(const float4*)(bet + c0);
  const float4 b1 = *(const float4*)(bet + c0 + 4);
  float o[8];
  o[0] = (y[0]-mu)*rstd*g0.x + b0.x;  o[1] = (y[1]-mu)*rstd*g0.y + b0.y;
  o[2] = (y[2]-mu)*rstd*g0.z + b0.z;  o[3] = (y[3]-mu)*rstd*g0.w + b0.w;
  o[4] = (y[4]-mu)*rstd*g1.x + b1.x;  o[5] = (y[5]-mu)*rstd*g1.y + b1.y;
  o[6] = (y[6]-mu)*rstd*g1.z + b1.z;  o[7] = (y[7]-mu)*rstd*g1.w + b1.w;
  *(float4*)(outF + base)     = make_float4(o[0], o[1], o[2], o[3]);
  *(float4*)(outF + base + 4) = make_float4(o[4], o[5], o[6], o[7]);
  if constexpr (WB){
    uint4 ob;
    ob.x = pack2(o[0], o[1]); ob.y = pack2(o[2], o[3]);
    ob.z = pack2(o[4], o[5]); ob.w = pack2(o[6], o[7]);
    *(uint4*)&outB[base] = ob;
  }
}

// ---------------------------------------------------------------------------
extern "C" void kernel_launch(void* const* d_in, const int* in_sizes, int n_in,
                              void* d_out, int out_size, void* d_ws, size_t ws_size,
                              hipStream_t stream)
{
  const float* seq   = (const float*)d_in[0];
  const float* emb_W = (const float*)d_in[1];
  const float* emb_b = (const float*)d_in[2];
  const float* Wq = (const float*)d_in[3];  const float* bq = (const float*)d_in[4];
  const float* Wk = (const float*)d_in[5];  const float* bk = (const float*)d_in[6];
  const float* Wv = (const float*)d_in[7];  const float* bv = (const float*)d_in[8];
  const float* Wo = (const float*)d_in[9];  const float* bo = (const float*)d_in[10];
  const float* ln_g = (const float*)d_in[11]; const float* ln_b = (const float*)d_in[12];
  const float* W1 = (const float*)d_in[13]; const float* b1 = (const float*)d_in[14];
  const float* W2 = (const float*)d_in[15]; const float* b2 = (const float*)d_in[16];

  char* ws = (char*)d_ws;
  size_t off = 0;
  auto take = [&](size_t bytes) -> void* {
    void* p = ws + off;
    off += (bytes + 255) & ~(size_t)255;
    return p;
  };
  bf16_t* seqB = (bf16_t*)take((size_t)SEQL*DM*2);
  float*  X    = (float*) take((size_t)SEQL*DM*4);
  bf16_t* XB   = (bf16_t*)take((size_t)SEQL*DM*2);
  bf16_t* Qf   = (bf16_t*)take((size_t)SEQL*DM*2);
  bf16_t* Kf   = (bf16_t*)take((size_t)SEQL*DM*2);
  bf16_t* Qhd  = (bf16_t*)take((size_t)SEQL*DM*2);
  bf16_t* Khd  = (bf16_t*)take((size_t)SEQL*DM*2);
  bf16_t* Vt   = (bf16_t*)take((size_t)SEQL*DM*2);
  bf16_t* Afl  = (bf16_t*)take((size_t)SEQL*DM*2);
  float*  Pp   = (float*) take((size_t)4*SEQL*DM*4);  // split-K partials (16 MB)
  float*  Xa   = (float*) take((size_t)SEQL*DM*4);
  bf16_t* XaB  = (bf16_t*)take((size_t)SEQL*DM*2);
  bf16_t* Hb   = (bf16_t*)take((size_t)SEQL*FFH*2);
  (void)ws_size; (void)in_sizes; (void)n_in; (void)out_size;

  // sequence fp32 -> bf16
  cvt_bf16<<<dim3(SEQL*DM/1024), 256, 0, stream>>>(seq, seqB);

  // embedding (split-K x4, 512 blocks) + posenc reduce
  gemmF<E_PART,0><<<dim3(512), 256, 0, stream>>>(seqB, emb_W, nullptr, nullptr,
      nullptr, nullptr, nullptr, Pp, nullptr, nullptr, nullptr, 16, DM, DM, 512);
  reduce_pos<<<SEQL, 256, 0, stream>>>(Pp, emb_b, X, XB);

  // fused QKV (384 blocks)
  gemmF<E_QKV,0><<<dim3(384), 256, 0, stream>>>(XB, Wq, Wk, Wv,
      bq, bk, bv, nullptr, Qf, Kf, Vt, 48, DM, DM, DM);
  permute_qk<<<dim3(SEQL,2), 256, 0, stream>>>(Qf, Kf, Qhd, Khd);

  // attention
  attn_kernel<<<dim3(16,16), 256, 0, stream>>>(Qhd, Khd, Vt, Afl);

  // output projection (split-K x4, k-permuted Wo) + residual + LN1
  gemmF<E_PART,1><<<dim3(512), 256, 0, stream>>>(Afl, Wo, nullptr, nullptr,
      nullptr, nullptr, nullptr, Pp, nullptr, nullptr, nullptr, 16, DM, DM, 512);
  reduce_ln<1><<<SEQL, 256, 0, stream>>>(Pp, bo, X, ln_g, ln_b, Xa, XaB);

  // FFN1 (512 blocks)
  gemmF<E_FFN1,0><<<dim3(512), 256, 0, stream>>>(XaB, W1, nullptr, nullptr,
      b1, nullptr, nullptr, nullptr, Hb, nullptr, nullptr, 64, FFH, DM, DM);

  // FFN2 (split-K x4, Kc=2048) + residual + LN2 -> out
  gemmF<E_PART,0><<<dim3(512), 256, 0, stream>>>(Hb, W2, nullptr, nullptr,
      nullptr, nullptr, nullptr, Pp, nullptr, nullptr, nullptr, 16, DM, FFH, 2048);
  reduce_ln<0><<<SEQL, 256, 0, stream>>>(Pp, b2, Xa, ln_g, ln_b, (float*)d_out, nullptr);
}